// Round 11
// baseline (136.662 us; speedup 1.0000x reference)
//
#include <hip/hip_runtime.h>
#include <stdint.h>

#define NBOX 8000
#define NPAD 8192

// ---- workspace layout (bytes) ----
#define ECNT_OFF 0                           // u32 edge count (zeroed by sort_decode)
#define SB(i)    (0x10000 + (size_t)(i) * 0x8000)
// sorted-by-rank arrays (float[8192] each):
// 0 bx, 1 by, 2 bw, 3 bh, 4 conf, 5 cls, 6 x1, 7 y1, 8 x2, 9 y2, 10 area
#define EDGE_OFF (size_t)0x200000            // u32 edges (i<<13|j); max 134MB < ws

__device__ __forceinline__ float sigmoidf_(float x) {
    return 1.0f / (1.0f + expf(-x));
}

// ---------------- fused decode + rank + scatter-to-sorted ----------------
// Block b owns source boxes [b*64, b*64+64). Keys (conf-sigmoid bits | idx
// tiebreak) are recomputed per tile from the conf channel (coalesced loads,
// ~10 VALU each). 4 threads/row split the 8192-key compare loop; partials
// summed in LDS. Wave 0 then fully decodes its 64 CONSECUTIVE boxes
// (coalesced loads; only the rank-indexed stores scatter) and writes the
// sorted arrays directly. Validity downstream = sconf[r] > 0.5 (sorted =>
// equivalent to r < V), so no count, no memset, no compaction.
__global__ __launch_bounds__(256) void sort_decode_kernel(const float* __restrict__ x,
                                                          const float* __restrict__ anchors,
                                                          unsigned char* __restrict__ ws) {
    __shared__ unsigned long long tile[256];
    __shared__ int partial[256];
    int tid  = threadIdx.x;
    int lane = tid & 63;
    int q    = tid >> 6;                     // quarter 0..3
    int b    = blockIdx.x;                   // 128 blocks
    int i    = (b << 6) + lane;              // source box owned by this lane

    if (b == 0 && tid == 0) *(unsigned int*)(ws + ECNT_OFF) = 0u;  // for mask_kernel

    // this lane's key (all 4 quarters compute the same ki for the same lane)
    unsigned long long ki;
    if (i < NBOX) {
        int a = i / 1600, pos = i - a * 1600;
        float c = sigmoidf_(x[a * 40000 + 4 * 1600 + pos]);
        ki = ((unsigned long long)__float_as_uint(c) << 32) | (unsigned long long)(8191 - i);
    } else {
        ki = (unsigned long long)(8191 - i); // pads sort last (conf bits = 0)
    }

    // rank ki against all 8192 keys (recomputed per tile)
    int cnt = 0;
    for (int tb = 0; tb < 32; ++tb) {
        int j = (tb << 8) + tid;
        unsigned long long kj;
        if (j < NBOX) {
            int aj = j / 1600, posj = j - aj * 1600;
            float cj = sigmoidf_(x[aj * 40000 + 4 * 1600 + posj]);
            kj = ((unsigned long long)__float_as_uint(cj) << 32) | (unsigned long long)(8191 - j);
        } else {
            kj = (unsigned long long)(8191 - j);
        }
        tile[tid] = kj;
        __syncthreads();
        const unsigned long long* tq = &tile[q << 6];
        #pragma unroll 16
        for (int jj = 0; jj < 64; ++jj) cnt += (tq[jj] > ki) ? 1 : 0;
        __syncthreads();
    }
    partial[tid] = cnt;
    __syncthreads();

    if (q == 0) {
        int r = partial[lane] + partial[64 + lane] + partial[128 + lane] + partial[192 + lane];
        float bx = 0.f, by = 0.f, bw = 0.f, bh = 0.f, conf = 0.f, cls = -1.0f;
        if (i < NBOX) {                      // full decode of own box (coalesced loads)
            int a = i / 1600, pos = i - a * 1600;
            int gy = pos / 40, gx = pos - gy * 40;
            const float* p = x + (size_t)a * 40000 + pos;
            float tx = sigmoidf_(p[0]);
            float ty = sigmoidf_(p[1600]);
            float tw = p[2 * 1600];
            float th = p[3 * 1600];
            conf = sigmoidf_(p[4 * 1600]);
            float best = -1.0f; int bi = 0;
            #pragma unroll
            for (int c = 0; c < 20; ++c) {   // first-max wins, matches jnp.argmax
                float v = sigmoidf_(p[(5 + c) * 1600]);
                if (v > best) { best = v; bi = c; }
            }
            float aw = anchors[a * 2 + 0];
            float ah = anchors[a * 2 + 1];
            bx = (tx + (float)gx) * 8.0f;
            by = (ty + (float)gy) * 8.0f;
            bw = expf(tw) * aw * 8.0f;
            bh = expf(th) * ah * 8.0f;
            cls = (float)bi;
        }
        {
        #pragma clang fp contract(off)
            float x1 = bx - bw / 2.0f, y1 = by - bh / 2.0f;
            float x2 = bx + bw / 2.0f, y2 = by + bh / 2.0f;
            float ar = fabsf((x2 - x1) * (y2 - y1));   // ref: recomputed from corners
            ((float*)(ws + SB(0)))[r]  = bx;  ((float*)(ws + SB(1)))[r]  = by;
            ((float*)(ws + SB(2)))[r]  = bw;  ((float*)(ws + SB(3)))[r]  = bh;
            ((float*)(ws + SB(4)))[r]  = conf; ((float*)(ws + SB(5)))[r] = cls;
            ((float*)(ws + SB(6)))[r]  = x1;  ((float*)(ws + SB(7)))[r]  = y1;
            ((float*)(ws + SB(8)))[r]  = x2;  ((float*)(ws + SB(9)))[r]  = y2;
            ((float*)(ws + SB(10)))[r] = ar;
        }
    }
}

// ---------------- suppression edges: (i<<13|j) for j>i, same cls, IoU>=0.5 ----------------
// Validity via sorted conf (> 0.5) instead of a count; block-uniform early
// exits read sconf at the tile heads (sorted descending).
__global__ __launch_bounds__(256) void mask_kernel(unsigned char* __restrict__ ws) {
#pragma clang fp contract(off)
    const float* sconf = (const float*)(ws + SB(4));
    int i0 = blockIdx.y * 256;
    int w  = blockIdx.x;
    int j0 = w * 64;
    if (sconf[i0] <= 0.5f) return;                 // whole i-tile invalid (sorted)
    if (sconf[j0] <= 0.5f) return;                 // whole j-word invalid
    if (j0 + 64 <= i0) return;                     // strictly sub-diagonal: empty
    int tid  = threadIdx.x;
    int lane = tid & 63;
    int i    = i0 + tid;

    const float* sx1 = (const float*)(ws + SB(6));
    const float* sy1 = (const float*)(ws + SB(7));
    const float* sx2 = (const float*)(ws + SB(8));
    const float* sy2 = (const float*)(ws + SB(9));
    const float* sar = (const float*)(ws + SB(10));
    const float* scl = (const float*)(ws + SB(5));

    __shared__ float cx1[64], cy1[64], cx2[64], cy2[64], car[64], ccl[64], ccf[64];
    if (tid < 64) {
        int j = j0 + tid;
        cx1[tid] = sx1[j]; cy1[tid] = sy1[j];
        cx2[tid] = sx2[j]; cy2[tid] = sy2[j];
        car[tid] = sar[j]; ccl[tid] = scl[j]; ccf[tid] = sconf[j];
    }
    __syncthreads();

    unsigned long long word = 0;
    if (sconf[i] > 0.5f && j0 + 64 > i + 1) {      // row i valid
        float x1i = sx1[i], y1i = sy1[i], x2i = sx2[i], y2i = sy2[i];
        float ai = sar[i], ci = scl[i];
        for (int jj = 0; jj < 64; ++jj) {
            int j = j0 + jj;
            if (j <= i) continue;
            if (ccf[jj] <= 0.5f) continue;         // col j invalid (== j >= V)
            if (ccl[jj] != ci) continue;
            float iw = fminf(x2i, cx2[jj]) - fmaxf(x1i, cx1[jj]);
            iw = fmaxf(iw, 0.0f);
            float ih = fminf(y2i, cy2[jj]) - fmaxf(y1i, cy1[jj]);
            ih = fmaxf(ih, 0.0f);
            float inter = iw * ih;
            float denom = ai + car[jj] - inter + 1e-6f;   // ((ai+aj)-inter)+eps, L-to-R
            if (inter / denom >= 0.5f) word |= (1ull << jj);
        }
    }

    // wave-aggregated edge emission (all 64 lanes participate)
    int pc = __popcll(word);
    int scan = pc;
    #pragma unroll
    for (int d = 1; d < 64; d <<= 1) {
        int t = __shfl_up(scan, d, 64);
        if (lane >= d) scan += t;
    }
    int total = __shfl(scan, 63, 64);
    if (total > 0) {
        unsigned int base = 0;
        if (lane == 63)
            base = atomicAdd((unsigned int*)(ws + ECNT_OFF), (unsigned int)total);
        base = (unsigned int)__shfl((int)base, 63, 64);
        unsigned int off = base + (unsigned int)(scan - pc);   // exclusive prefix
        unsigned int* edges = (unsigned int*)(ws + EDGE_OFF);
        unsigned long long t = word;
        while (t) {
            int bit = __builtin_ctzll(t);
            t &= t - 1ull;
            edges[off++] = ((unsigned int)i << 13) | (unsigned int)(j0 + bit);
        }
    }
}

// ---------------- NMS via Jacobi fixed point + fused output ----------------
// Greedy NMS == unique fixed point of a[j] = valid[j] & ~OR_{i<j, edge} a[i].
// Single block, LDS bitmaps, exact change-detection. Output reads the sorted
// arrays coalesced (no indirection).
__global__ __launch_bounds__(1024, 1) void nms_out_kernel(unsigned char* __restrict__ ws,
                                                          float* __restrict__ out) {
    int tid  = threadIdx.x;
    int lane = tid & 63;
    unsigned int E = *(const unsigned int*)(ws + ECNT_OFF);
    const unsigned int* edges = (const unsigned int*)(ws + EDGE_OFF);
    const float* sconf = (const float*)(ws + SB(4));

    __shared__ unsigned long long valid[128], alive[128], supp[128];
    __shared__ int flag;

    for (int c = tid >> 6; c < 128; c += 16) {     // 16 waves, 8 chunks each
        unsigned long long m = __ballot(sconf[(c << 6) + lane] > 0.5f);
        if (lane == 0) valid[c] = m;
    }
    __syncthreads();
    if (tid < 128) alive[tid] = valid[tid];
    __syncthreads();

    for (;;) {
        if (tid < 128) supp[tid] = 0ull;
        __syncthreads();
        for (unsigned int e = tid; e < E; e += 1024) {
            unsigned int u = edges[e];
            unsigned int i = u >> 13, j = u & 8191u;
            if ((alive[i >> 6] >> (i & 63)) & 1ull)
                atomicOr(&supp[j >> 6], 1ull << (j & 63));
        }
        if (tid == 0) flag = 0;
        __syncthreads();
        if (tid < 128) {
            unsigned long long na = valid[tid] & ~supp[tid];
            if (na != alive[tid]) { alive[tid] = na; flag = 1; }
        }
        __syncthreads();
        if (!flag) break;
    }

    // fused output: kept ranks get sorted box values, everything else zero
    for (int r = tid; r < NBOX; r += 1024) {
        bool keep = (alive[r >> 6] >> (r & 63)) & 1ull;
        float o0 = 0.f, o1 = 0.f, o2 = 0.f, o3 = 0.f, o4 = 0.f, o5 = 0.f;
        if (keep) {
            o0 = ((const float*)(ws + SB(0)))[r];
            o1 = ((const float*)(ws + SB(1)))[r];
            o2 = ((const float*)(ws + SB(2)))[r];
            o3 = ((const float*)(ws + SB(3)))[r];
            o4 = ((const float*)(ws + SB(4)))[r];
            o5 = ((const float*)(ws + SB(5)))[r];
        }
        out[r * 6 + 0] = o0;
        out[r * 6 + 1] = o1;
        out[r * 6 + 2] = o2;
        out[r * 6 + 3] = o3;
        out[r * 6 + 4] = o4;
        out[r * 6 + 5] = o5;
    }
}

extern "C" void kernel_launch(void* const* d_in, const int* in_sizes, int n_in,
                              void* d_out, int out_size, void* d_ws, size_t ws_size,
                              hipStream_t stream) {
    const float* x       = (const float*)d_in[0];
    const float* anchors = (const float*)d_in[1];
    float* out           = (float*)d_out;
    unsigned char* ws    = (unsigned char*)d_ws;

    sort_decode_kernel<<<NPAD / 64, 256, 0, stream>>>(x, anchors, ws);
    dim3 mgrid(128, NPAD / 256);
    mask_kernel<<<mgrid, 256, 0, stream>>>(ws);
    nms_out_kernel<<<1, 1024, 0, stream>>>(ws, out);
}

// Round 12
// 120.167 us; speedup vs baseline: 1.1373x; 1.1373x over previous
//
#include <hip/hip_runtime.h>
#include <stdint.h>

#define NBOX 8000
#define NPAD 8192

// ---- workspace layout (bytes) ----
#define ECNT_OFF 0                           // u32 edge count (zeroed by sort_decode)
#define SB(i)    (0x10000 + (size_t)(i) * 0x8000)
// sorted-by-rank arrays (float[8192] each):
// 0 bx, 1 by, 2 bw, 3 bh, 4 conf, 5 cls, 6 x1, 7 y1, 8 x2, 9 y2, 10 area
#define EDGE_OFF (size_t)0x200000            // u32 edges (i<<13|j); max 134MB < ws

__device__ __forceinline__ float sigmoidf_(float x) {
    return 1.0f / (1.0f + expf(-x));
}

// ---------------- fused decode + rank + scatter-to-sorted ----------------
// Block b owns source boxes [b*64, b*64+64).
// Phase 1: 512 threads materialize ALL 8192 keys into LDS once (coalesced
//          conf-channel loads + sigmoid). ONE barrier.
// Phase 2: wave w (0..7) ranks the block's 64 row-keys against key segment
//          [w*1024,(w+1)*1024): every lane reads the SAME LDS address per
//          step (broadcast, conflict-free), zero barriers in the hot loop.
// Phase 3: wave 0 sums the 8 partials per row, fully decodes its 64
//          CONSECUTIVE boxes (coalesced loads; only rank-indexed stores
//          scatter) and writes the sorted arrays directly.
// Validity downstream = sconf[r] > 0.5 (sorted => equivalent to r < V):
// no count, no memset, no compaction.
__global__ __launch_bounds__(512) void sort_decode_kernel(const float* __restrict__ x,
                                                          const float* __restrict__ anchors,
                                                          unsigned char* __restrict__ ws) {
    __shared__ unsigned long long keys[NPAD];    // 64 KB
    __shared__ int partial[512];
    int tid  = threadIdx.x;
    int lane = tid & 63;
    int wv   = tid >> 6;                         // wave 0..7
    int b    = blockIdx.x;                       // 128 blocks

    if (b == 0 && tid == 0) *(unsigned int*)(ws + ECNT_OFF) = 0u;   // for mask_kernel

    // ---- phase 1: all keys -> LDS (16 coalesced loads/thread) ----
    for (int t = tid; t < NPAD; t += 512) {
        unsigned long long k;
        if (t < NBOX) {
            int a = t / 1600, pos = t - a * 1600;
            float c = sigmoidf_(x[a * 40000 + 4 * 1600 + pos]);
            k = ((unsigned long long)__float_as_uint(c) << 32) | (unsigned long long)(8191 - t);
        } else {
            k = (unsigned long long)(8191 - t);  // pads sort last (conf bits = 0)
        }
        keys[t] = k;
    }
    __syncthreads();

    // ---- phase 2: rank; wave wv vs segment wv (broadcast LDS reads) ----
    int i = (b << 6) + lane;                     // source box owned by this lane
    unsigned long long ki = keys[i];
    const unsigned long long* ks = &keys[wv << 10];
    int cnt = 0;
    #pragma unroll 8
    for (int jj = 0; jj < 1024; ++jj) cnt += (ks[jj] > ki) ? 1 : 0;
    partial[(wv << 6) + lane] = cnt;
    __syncthreads();

    // ---- phase 3: wave 0 sums partials, decodes, scatter-writes ----
    if (wv == 0) {
        int r = 0;
        #pragma unroll
        for (int s = 0; s < 8; ++s) r += partial[(s << 6) + lane];

        float bx = 0.f, by = 0.f, bw = 0.f, bh = 0.f, conf = 0.f, cls = -1.0f;
        if (i < NBOX) {                          // full decode (coalesced channel loads)
            int a = i / 1600, pos = i - a * 1600;
            int gy = pos / 40, gx = pos - gy * 40;
            const float* p = x + (size_t)a * 40000 + pos;
            float tx = sigmoidf_(p[0]);
            float ty = sigmoidf_(p[1600]);
            float tw = p[2 * 1600];
            float th = p[3 * 1600];
            conf = sigmoidf_(p[4 * 1600]);
            float best = -1.0f; int bi = 0;
            #pragma unroll
            for (int c = 0; c < 20; ++c) {       // first-max wins, matches jnp.argmax
                float v = sigmoidf_(p[(5 + c) * 1600]);
                if (v > best) { best = v; bi = c; }
            }
            float aw = anchors[a * 2 + 0];
            float ah = anchors[a * 2 + 1];
            bx = (tx + (float)gx) * 8.0f;
            by = (ty + (float)gy) * 8.0f;
            bw = expf(tw) * aw * 8.0f;
            bh = expf(th) * ah * 8.0f;
            cls = (float)bi;
        }
        {
        #pragma clang fp contract(off)
            float x1 = bx - bw / 2.0f, y1 = by - bh / 2.0f;
            float x2 = bx + bw / 2.0f, y2 = by + bh / 2.0f;
            float ar = fabsf((x2 - x1) * (y2 - y1));   // ref: recomputed from corners
            ((float*)(ws + SB(0)))[r]  = bx;  ((float*)(ws + SB(1)))[r]  = by;
            ((float*)(ws + SB(2)))[r]  = bw;  ((float*)(ws + SB(3)))[r]  = bh;
            ((float*)(ws + SB(4)))[r]  = conf; ((float*)(ws + SB(5)))[r] = cls;
            ((float*)(ws + SB(6)))[r]  = x1;  ((float*)(ws + SB(7)))[r]  = y1;
            ((float*)(ws + SB(8)))[r]  = x2;  ((float*)(ws + SB(9)))[r]  = y2;
            ((float*)(ws + SB(10)))[r] = ar;
        }
    }
}

// ---------------- suppression edges: (i<<13|j) for j>i, same cls, IoU>=0.5 ----------------
// Validity via sorted conf (> 0.5); block-uniform early exits read sconf at
// tile heads (sorted descending). Wave-aggregated edge compaction.
__global__ __launch_bounds__(256) void mask_kernel(unsigned char* __restrict__ ws) {
#pragma clang fp contract(off)
    const float* sconf = (const float*)(ws + SB(4));
    int i0 = blockIdx.y * 256;
    int w  = blockIdx.x;
    int j0 = w * 64;
    if (sconf[i0] <= 0.5f) return;                 // whole i-tile invalid (sorted)
    if (sconf[j0] <= 0.5f) return;                 // whole j-word invalid
    if (j0 + 64 <= i0) return;                     // strictly sub-diagonal: empty
    int tid  = threadIdx.x;
    int lane = tid & 63;
    int i    = i0 + tid;

    const float* sx1 = (const float*)(ws + SB(6));
    const float* sy1 = (const float*)(ws + SB(7));
    const float* sx2 = (const float*)(ws + SB(8));
    const float* sy2 = (const float*)(ws + SB(9));
    const float* sar = (const float*)(ws + SB(10));
    const float* scl = (const float*)(ws + SB(5));

    __shared__ float cx1[64], cy1[64], cx2[64], cy2[64], car[64], ccl[64], ccf[64];
    if (tid < 64) {
        int j = j0 + tid;
        cx1[tid] = sx1[j]; cy1[tid] = sy1[j];
        cx2[tid] = sx2[j]; cy2[tid] = sy2[j];
        car[tid] = sar[j]; ccl[tid] = scl[j]; ccf[tid] = sconf[j];
    }
    __syncthreads();

    unsigned long long word = 0;
    if (sconf[i] > 0.5f && j0 + 64 > i + 1) {      // row i valid
        float x1i = sx1[i], y1i = sy1[i], x2i = sx2[i], y2i = sy2[i];
        float ai = sar[i], ci = scl[i];
        for (int jj = 0; jj < 64; ++jj) {
            int j = j0 + jj;
            if (j <= i) continue;
            if (ccf[jj] <= 0.5f) continue;         // col j invalid (== j >= V)
            if (ccl[jj] != ci) continue;
            float iw = fminf(x2i, cx2[jj]) - fmaxf(x1i, cx1[jj]);
            iw = fmaxf(iw, 0.0f);
            float ih = fminf(y2i, cy2[jj]) - fmaxf(y1i, cy1[jj]);
            ih = fmaxf(ih, 0.0f);
            float inter = iw * ih;
            float denom = ai + car[jj] - inter + 1e-6f;   // ((ai+aj)-inter)+eps, L-to-R
            if (inter / denom >= 0.5f) word |= (1ull << jj);
        }
    }

    // wave-aggregated edge emission (all 64 lanes participate)
    int pc = __popcll(word);
    int scan = pc;
    #pragma unroll
    for (int d = 1; d < 64; d <<= 1) {
        int t = __shfl_up(scan, d, 64);
        if (lane >= d) scan += t;
    }
    int total = __shfl(scan, 63, 64);
    if (total > 0) {
        unsigned int base = 0;
        if (lane == 63)
            base = atomicAdd((unsigned int*)(ws + ECNT_OFF), (unsigned int)total);
        base = (unsigned int)__shfl((int)base, 63, 64);
        unsigned int off = base + (unsigned int)(scan - pc);   // exclusive prefix
        unsigned int* edges = (unsigned int*)(ws + EDGE_OFF);
        unsigned long long t = word;
        while (t) {
            int bit = __builtin_ctzll(t);
            t &= t - 1ull;
            edges[off++] = ((unsigned int)i << 13) | (unsigned int)(j0 + bit);
        }
    }
}

// ---------------- NMS via Jacobi fixed point + fused output ----------------
// Greedy NMS == unique fixed point of a[j] = valid[j] & ~OR_{i<j, edge} a[i].
// Single block, LDS bitmaps, exact change-detection. Output reads the sorted
// arrays coalesced (no indirection).
__global__ __launch_bounds__(1024, 1) void nms_out_kernel(unsigned char* __restrict__ ws,
                                                          float* __restrict__ out) {
    int tid  = threadIdx.x;
    int lane = tid & 63;
    unsigned int E = *(const unsigned int*)(ws + ECNT_OFF);
    const unsigned int* edges = (const unsigned int*)(ws + EDGE_OFF);
    const float* sconf = (const float*)(ws + SB(4));

    __shared__ unsigned long long valid[128], alive[128], supp[128];
    __shared__ int flag;

    for (int c = tid >> 6; c < 128; c += 16) {     // 16 waves, 8 chunks each
        unsigned long long m = __ballot(sconf[(c << 6) + lane] > 0.5f);
        if (lane == 0) valid[c] = m;
    }
    __syncthreads();
    if (tid < 128) alive[tid] = valid[tid];
    __syncthreads();

    for (;;) {
        if (tid < 128) supp[tid] = 0ull;
        __syncthreads();
        for (unsigned int e = tid; e < E; e += 1024) {
            unsigned int u = edges[e];
            unsigned int i = u >> 13, j = u & 8191u;
            if ((alive[i >> 6] >> (i & 63)) & 1ull)
                atomicOr(&supp[j >> 6], 1ull << (j & 63));
        }
        if (tid == 0) flag = 0;
        __syncthreads();
        if (tid < 128) {
            unsigned long long na = valid[tid] & ~supp[tid];
            if (na != alive[tid]) { alive[tid] = na; flag = 1; }
        }
        __syncthreads();
        if (!flag) break;
    }

    // fused output: kept ranks get sorted box values, everything else zero
    for (int r = tid; r < NBOX; r += 1024) {
        bool keep = (alive[r >> 6] >> (r & 63)) & 1ull;
        float o0 = 0.f, o1 = 0.f, o2 = 0.f, o3 = 0.f, o4 = 0.f, o5 = 0.f;
        if (keep) {
            o0 = ((const float*)(ws + SB(0)))[r];
            o1 = ((const float*)(ws + SB(1)))[r];
            o2 = ((const float*)(ws + SB(2)))[r];
            o3 = ((const float*)(ws + SB(3)))[r];
            o4 = ((const float*)(ws + SB(4)))[r];
            o5 = ((const float*)(ws + SB(5)))[r];
        }
        out[r * 6 + 0] = o0;
        out[r * 6 + 1] = o1;
        out[r * 6 + 2] = o2;
        out[r * 6 + 3] = o3;
        out[r * 6 + 4] = o4;
        out[r * 6 + 5] = o5;
    }
}

extern "C" void kernel_launch(void* const* d_in, const int* in_sizes, int n_in,
                              void* d_out, int out_size, void* d_ws, size_t ws_size,
                              hipStream_t stream) {
    const float* x       = (const float*)d_in[0];
    const float* anchors = (const float*)d_in[1];
    float* out           = (float*)d_out;
    unsigned char* ws    = (unsigned char*)d_ws;

    sort_decode_kernel<<<NPAD / 64, 512, 0, stream>>>(x, anchors, ws);
    dim3 mgrid(128, NPAD / 256);
    mask_kernel<<<mgrid, 256, 0, stream>>>(ws);
    nms_out_kernel<<<1, 1024, 0, stream>>>(ws, out);
}